// Round 1
// baseline (4883.444 us; speedup 1.0000x reference)
//
#include <hip/hip_runtime.h>

#define TT 512
#define HH 50

__device__ __forceinline__ float sigf(float x) {
    return 1.0f / (1.0f + __expf(-x));
}
__device__ __forceinline__ float tanhfast(float x) {
    // tanh(x) = 1 - 2/(e^{2x}+1); exact limits at +-inf, branch-free
    return 1.0f - 2.0f / (__expf(2.0f * x) + 1.0f);
}

// 4 parallel 50-length dot products: a_g += sum_k w[g][k] * hp[k]
// hp points to LDS (16B-aligned base), uniform across the wave (broadcast reads).
__device__ __forceinline__ void dot50(const float (&w)[4][HH], const float* hp,
                                      float& a0, float& a1, float& a2, float& a3) {
#pragma unroll
    for (int q = 0; q < 12; ++q) {
        float4 h4 = *reinterpret_cast<const float4*>(&hp[4 * q]);
        a0 = fmaf(h4.x, w[0][4 * q + 0], a0);
        a0 = fmaf(h4.y, w[0][4 * q + 1], a0);
        a0 = fmaf(h4.z, w[0][4 * q + 2], a0);
        a0 = fmaf(h4.w, w[0][4 * q + 3], a0);
        a1 = fmaf(h4.x, w[1][4 * q + 0], a1);
        a1 = fmaf(h4.y, w[1][4 * q + 1], a1);
        a1 = fmaf(h4.z, w[1][4 * q + 2], a1);
        a1 = fmaf(h4.w, w[1][4 * q + 3], a1);
        a2 = fmaf(h4.x, w[2][4 * q + 0], a2);
        a2 = fmaf(h4.y, w[2][4 * q + 1], a2);
        a2 = fmaf(h4.z, w[2][4 * q + 2], a2);
        a2 = fmaf(h4.w, w[2][4 * q + 3], a2);
        a3 = fmaf(h4.x, w[3][4 * q + 0], a3);
        a3 = fmaf(h4.y, w[3][4 * q + 1], a3);
        a3 = fmaf(h4.z, w[3][4 * q + 2], a3);
        a3 = fmaf(h4.w, w[3][4 * q + 3], a3);
    }
    float2 h2 = *reinterpret_cast<const float2*>(&hp[48]);
    a0 = fmaf(h2.x, w[0][48], a0); a0 = fmaf(h2.y, w[0][49], a0);
    a1 = fmaf(h2.x, w[1][48], a1); a1 = fmaf(h2.y, w[1][49], a1);
    a2 = fmaf(h2.x, w[2][48], a2); a2 = fmaf(h2.y, w[2][49], a2);
    a3 = fmaf(h2.x, w[3][48], a3); a3 = fmaf(h2.y, w[3][49], a3);
}

// One block = one batch element, 3 waves:
//  wave0: layer0 recurrent step (weights W_hh0 in VGPRs)
//  wave1: layer1 input matmul  xg1 = W_ih1 * h0  (weights in VGPRs)
//  wave2: layer1 recurrent step (weights W_hh1 in VGPRs) + final MLP head
// Software pipeline over t, double-buffered LDS handoff, 1 barrier/tick.
__global__ __launch_bounds__(192, 2)
void lstm2_pipeline_kernel(const float* __restrict__ x,
                           const float* __restrict__ W_ih0, const float* __restrict__ W_hh0,
                           const float* __restrict__ b_ih0, const float* __restrict__ b_hh0,
                           const float* __restrict__ W_ih1, const float* __restrict__ W_hh1,
                           const float* __restrict__ b_ih1, const float* __restrict__ b_hh1,
                           const float* __restrict__ W1, const float* __restrict__ b1,
                           const float* __restrict__ W2, const float* __restrict__ b2,
                           const float* __restrict__ W3, const float* __restrict__ b3,
                           float* __restrict__ out)
{
    const int b    = blockIdx.x;
    const int tid  = threadIdx.x;
    const int wid  = tid >> 6;
    const int lane = tid & 63;
    const int js   = (lane < HH) ? lane : 0;   // clamped unit index (lanes 50..63 compute garbage, never stored)
    const bool act = (lane < HH);

    __shared__ __align__(16) float A[2][52];        // h0 double buffer (padded to 52 for float4 reads)
    __shared__ __align__(16) float Bx[2][4 * HH];   // xg1 double buffer, layout [gate][unit]
    __shared__ __align__(16) float C[52];           // h1 broadcast buffer
    __shared__ float D1[32];
    __shared__ float D2[16];

    if (tid < 52) { A[0][tid] = 0.0f; A[1][tid] = 0.0f; C[tid] = 0.0f; }

    // --- Per-wave stationary weights: lane j holds rows {j, 50+j, 100+j, 150+j} (i,f,g,o) ---
    const float* Wm = (wid == 0) ? W_hh0 : (wid == 1) ? W_ih1 : W_hh1;
    float w[4][HH];
#pragma unroll
    for (int g = 0; g < 4; ++g)
#pragma unroll
        for (int k = 0; k < HH; ++k)
            w[g][k] = Wm[(g * HH + js) * HH + k];

    float bias[4], wih0[4];
#pragma unroll
    for (int g = 0; g < 4; ++g) {
        const int r = g * HH + js;
        bias[g] = (wid == 0) ? (b_ih0[r] + b_hh0[r]) : (wid == 1) ? b_ih1[r] : b_hh1[r];
        wih0[g] = (wid == 0) ? W_ih0[r] : 0.0f;
    }

    float c_st = 0.0f;           // cell state (wave0: c0, wave2: c1)
    const float* xrow = x + (size_t)b * TT;
    float x_cur = (wid == 0) ? xrow[0] : 0.0f;
    float x_nxt = 0.0f;

    __syncthreads();

    for (int tau = 0; tau < TT + 2; ++tau) {
        if (wid == 0) {
            if (tau < TT) {
                if (tau + 1 < TT) x_nxt = xrow[tau + 1];   // prefetch next-tick x
                float a0 = fmaf(x_cur, wih0[0], bias[0]);
                float a1 = fmaf(x_cur, wih0[1], bias[1]);
                float a2 = fmaf(x_cur, wih0[2], bias[2]);
                float a3 = fmaf(x_cur, wih0[3], bias[3]);
                dot50(w, A[(tau + 1) & 1], a0, a1, a2, a3);
                float i = sigf(a0), f = sigf(a1), g = tanhfast(a2), o = sigf(a3);
                c_st = fmaf(f, c_st, i * g);
                float h = o * tanhfast(c_st);
                if (act) A[tau & 1][lane] = h;
                x_cur = x_nxt;
            }
        } else if (wid == 1) {
            if (tau >= 1 && tau <= TT) {
                float a0 = bias[0], a1 = bias[1], a2 = bias[2], a3 = bias[3];
                dot50(w, A[(tau + 1) & 1], a0, a1, a2, a3);
                if (act) {
                    float* bx = Bx[tau & 1];
                    bx[lane] = a0; bx[HH + lane] = a1;
                    bx[2 * HH + lane] = a2; bx[3 * HH + lane] = a3;
                }
            }
        } else {
            if (tau >= 2) {
                const float* bx = Bx[(tau + 1) & 1];
                float a0 = bias[0] + bx[js];
                float a1 = bias[1] + bx[HH + js];
                float a2 = bias[2] + bx[2 * HH + js];
                float a3 = bias[3] + bx[3 * HH + js];
                dot50(w, C, a0, a1, a2, a3);
                float i = sigf(a0), f = sigf(a1), g = tanhfast(a2), o = sigf(a3);
                c_st = fmaf(f, c_st, i * g);
                float h = o * tanhfast(c_st);
                if (act) C[lane] = h;   // same-wave RAW->WAR on C, ordered by program order + next barrier
            }
        }
        __syncthreads();
    }

    // --- MLP head on h1_final (in C), done by wave0; barriers reached by all threads ---
    if (wid == 0 && lane < 32) {
        float z = b1[lane];
#pragma unroll
        for (int k = 0; k < HH; ++k) z = fmaf(W1[lane * HH + k], C[k], z);
        D1[lane] = fmaxf(z, 0.0f);
    }
    __syncthreads();
    if (wid == 0 && lane < 16) {
        float z = b2[lane];
#pragma unroll
        for (int k = 0; k < 32; ++k) z = fmaf(W2[lane * 32 + k], D1[k], z);
        D2[lane] = fmaxf(z, 0.0f);
    }
    __syncthreads();
    if (wid == 0 && lane == 0) {
        float z = b3[0];
#pragma unroll
        for (int k = 0; k < 16; ++k) z = fmaf(W3[k], D2[k], z);
        out[b] = z;
    }
}

extern "C" void kernel_launch(void* const* d_in, const int* in_sizes, int n_in,
                              void* d_out, int out_size, void* d_ws, size_t ws_size,
                              hipStream_t stream) {
    const float* x     = (const float*)d_in[0];
    const float* W_ih0 = (const float*)d_in[1];
    const float* W_hh0 = (const float*)d_in[2];
    const float* b_ih0 = (const float*)d_in[3];
    const float* b_hh0 = (const float*)d_in[4];
    const float* W_ih1 = (const float*)d_in[5];
    const float* W_hh1 = (const float*)d_in[6];
    const float* b_ih1 = (const float*)d_in[7];
    const float* b_hh1 = (const float*)d_in[8];
    const float* W1    = (const float*)d_in[9];
    const float* b1    = (const float*)d_in[10];
    const float* W2    = (const float*)d_in[11];
    const float* b2    = (const float*)d_in[12];
    const float* W3    = (const float*)d_in[13];
    const float* b3    = (const float*)d_in[14];

    const int B = in_sizes[0] / TT;   // x is [B, T, 1]

    lstm2_pipeline_kernel<<<dim3(B), dim3(192), 0, stream>>>(
        x, W_ih0, W_hh0, b_ih0, b_hh0, W_ih1, W_hh1, b_ih1, b_hh1,
        W1, b1, W2, b2, W3, b3, (float*)d_out);
}

// Round 2
// 4615.978 us; speedup vs baseline: 1.0579x; 1.0579x over previous
//
#include <hip/hip_runtime.h>

#define TT 512
#define HH 50

__device__ __forceinline__ float sigf(float x) {
    return 1.0f / (1.0f + __expf(-x));
}
__device__ __forceinline__ float tanhfast(float x) {
    // tanh(x) = 1 - 2/(e^{2x}+1); exact limits at +-inf, branch-free
    return 1.0f - 2.0f / (__expf(2.0f * x) + 1.0f);
}

// 2 parallel 50-length dot products: a_g += sum_k w[g][k] * hp[k]
// hp is an LDS pointer, uniform across the wave (broadcast reads, conflict-free).
__device__ __forceinline__ void dot50x2(const float (&w)[2][HH], const float* hp,
                                        float& a0, float& a1) {
#pragma unroll
    for (int q = 0; q < 12; ++q) {
        float4 h4 = *reinterpret_cast<const float4*>(&hp[4 * q]);
        a0 = fmaf(h4.x, w[0][4 * q + 0], a0);
        a0 = fmaf(h4.y, w[0][4 * q + 1], a0);
        a0 = fmaf(h4.z, w[0][4 * q + 2], a0);
        a0 = fmaf(h4.w, w[0][4 * q + 3], a0);
        a1 = fmaf(h4.x, w[1][4 * q + 0], a1);
        a1 = fmaf(h4.y, w[1][4 * q + 1], a1);
        a1 = fmaf(h4.z, w[1][4 * q + 2], a1);
        a1 = fmaf(h4.w, w[1][4 * q + 3], a1);
    }
    float2 h2 = *reinterpret_cast<const float2*>(&hp[48]);
    a0 = fmaf(h2.x, w[0][48], a0); a0 = fmaf(h2.y, w[0][49], a0);
    a1 = fmaf(h2.x, w[1][48], a1); a1 = fmaf(h2.y, w[1][49], a1);
}

// One block = one batch element, 6 waves = 3 pairs:
//   pair p=0: layer0 recurrent (W_hh0), p=1: layer1 input matmul (W_ih1),
//   pair p=2: layer1 recurrent (W_hh1).
// Within a pair, wave s=0 owns gates (i,f), s=1 owns gates (g,o): 100 weights/lane
// -> fits the 128-VGPR occupancy class (4 waves/SIMD), no spill by construction.
// Two barriers per tick: M phase (matmuls -> gate pre-activations in LDS),
// P phase (s=0 wave of each recurrent pair does the pointwise c/h update).
// Software pipeline over t (skew: p0 at t, p1 at t-1, p2 at t-2).
__global__ __launch_bounds__(384, 4)
void lstm2_pipeline6_kernel(const float* __restrict__ x,
                            const float* __restrict__ W_ih0, const float* __restrict__ W_hh0,
                            const float* __restrict__ b_ih0, const float* __restrict__ b_hh0,
                            const float* __restrict__ W_ih1, const float* __restrict__ W_hh1,
                            const float* __restrict__ b_ih1, const float* __restrict__ b_hh1,
                            const float* __restrict__ W1, const float* __restrict__ b1,
                            const float* __restrict__ W2, const float* __restrict__ b2,
                            const float* __restrict__ W3, const float* __restrict__ b3,
                            float* __restrict__ out)
{
    const int b    = blockIdx.x;
    const int tid  = threadIdx.x;
    const int wid  = tid >> 6;     // 0..5
    const int p    = wid >> 1;     // matrix: 0=W_hh0, 1=W_ih1, 2=W_hh1
    const int s    = wid & 1;      // gate half: 0 -> (i,f), 1 -> (g,o)
    const int lane = tid & 63;
    const int js   = (lane < HH) ? lane : 0;   // clamped unit index
    const bool act = (lane < HH);

    __shared__ __align__(16) float h0[52];         // layer0 hidden (single buffer: RAW/WAR split by barriers)
    __shared__ __align__(16) float h1[52];         // layer1 hidden
    __shared__ __align__(16) float G0[4][52];      // layer0 gate pre-activations [gate][unit]
    __shared__ __align__(16) float G2[4][52];      // layer1 gate pre-activations
    __shared__ __align__(16) float Bx[2][4][52];   // xg1 double buffer [buf][gate][unit]
    __shared__ float D1[32];
    __shared__ float D2[16];

    if (tid < 52) { h0[tid] = 0.0f; h1[tid] = 0.0f; }

    // --- Stationary weights: lane j of wave (p,s) holds rows {2s*50+j, (2s+1)*50+j} ---
    const float* Wm = (p == 0) ? W_hh0 : (p == 1) ? W_ih1 : W_hh1;
    float w[2][HH];
#pragma unroll
    for (int g = 0; g < 2; ++g) {
        const int row = (2 * s + g) * HH + js;
#pragma unroll
        for (int k = 0; k < HH; ++k)
            w[g][k] = Wm[row * HH + k];
    }

    float bias[2], wx[2];
#pragma unroll
    for (int g = 0; g < 2; ++g) {
        const int r = (2 * s + g) * HH + js;
        bias[g] = (p == 0) ? (b_ih0[r] + b_hh0[r]) : (p == 1) ? b_ih1[r] : b_hh1[r];
        wx[g]   = (p == 0) ? W_ih0[r] : 0.0f;
    }

    float c_st = 0.0f;                 // cell state (p0s0: layer0, p2s0: layer1)
    const float* xrow = x + (size_t)b * TT;
    float x_cur = (p == 0) ? xrow[0] : 0.0f;
    float x_nxt = 0.0f;

    __syncthreads();

    for (int tau = 0; tau < TT + 2; ++tau) {
        // ================= M phase: matmuls =================
        if (p == 0) {
            if (tau < TT) {                         // step t = tau, reads h0(t-1)
                if (tau + 1 < TT) x_nxt = xrow[tau + 1];
                float a0 = fmaf(x_cur, wx[0], bias[0]);
                float a1 = fmaf(x_cur, wx[1], bias[1]);
                dot50x2(w, h0, a0, a1);
                if (act) { G0[2 * s][lane] = a0; G0[2 * s + 1][lane] = a1; }
                x_cur = x_nxt;
            }
        } else if (p == 1) {
            if (tau >= 1 && tau <= TT) {            // xg1 for step t = tau-1, reads h0(t)
                float a0 = bias[0], a1 = bias[1];
                dot50x2(w, h0, a0, a1);
                if (act) {
                    Bx[tau & 1][2 * s][lane]     = a0;
                    Bx[tau & 1][2 * s + 1][lane] = a1;
                }
            }
        } else {
            if (tau >= 2) {                         // step t = tau-2, reads h1(t-1), xg1(t)
                const int buf = (tau + 1) & 1;
                float a0 = bias[0] + Bx[buf][2 * s][js];
                float a1 = bias[1] + Bx[buf][2 * s + 1][js];
                dot50x2(w, h1, a0, a1);
                if (act) { G2[2 * s][lane] = a0; G2[2 * s + 1][lane] = a1; }
            }
        }
        __syncthreads();
        // ================= P phase: pointwise =================
        if (s == 0 && act) {
            if (p == 0 && tau < TT) {
                float i = sigf(G0[0][lane]);
                float f = sigf(G0[1][lane]);
                float g = tanhfast(G0[2][lane]);
                float o = sigf(G0[3][lane]);
                c_st = fmaf(f, c_st, i * g);
                h0[lane] = o * tanhfast(c_st);
            } else if (p == 2 && tau >= 2) {
                float i = sigf(G2[0][lane]);
                float f = sigf(G2[1][lane]);
                float g = tanhfast(G2[2][lane]);
                float o = sigf(G2[3][lane]);
                c_st = fmaf(f, c_st, i * g);
                h1[lane] = o * tanhfast(c_st);
            }
        }
        __syncthreads();
    }

    // --- MLP head on final h1 (in LDS); wave 0 computes, barriers hit by all ---
    if (wid == 0 && lane < 32) {
        float z = b1[lane];
#pragma unroll
        for (int k = 0; k < HH; ++k) z = fmaf(W1[lane * HH + k], h1[k], z);
        D1[lane] = fmaxf(z, 0.0f);
    }
    __syncthreads();
    if (wid == 0 && lane < 16) {
        float z = b2[lane];
#pragma unroll
        for (int k = 0; k < 32; ++k) z = fmaf(W2[lane * 32 + k], D1[k], z);
        D2[lane] = fmaxf(z, 0.0f);
    }
    __syncthreads();
    if (wid == 0 && lane == 0) {
        float z = b3[0];
#pragma unroll
        for (int k = 0; k < 16; ++k) z = fmaf(W3[k], D2[k], z);
        out[b] = z;
    }
}

extern "C" void kernel_launch(void* const* d_in, const int* in_sizes, int n_in,
                              void* d_out, int out_size, void* d_ws, size_t ws_size,
                              hipStream_t stream) {
    const float* x     = (const float*)d_in[0];
    const float* W_ih0 = (const float*)d_in[1];
    const float* W_hh0 = (const float*)d_in[2];
    const float* b_ih0 = (const float*)d_in[3];
    const float* b_hh0 = (const float*)d_in[4];
    const float* W_ih1 = (const float*)d_in[5];
    const float* W_hh1 = (const float*)d_in[6];
    const float* b_ih1 = (const float*)d_in[7];
    const float* b_hh1 = (const float*)d_in[8];
    const float* W1    = (const float*)d_in[9];
    const float* b1    = (const float*)d_in[10];
    const float* W2    = (const float*)d_in[11];
    const float* b2    = (const float*)d_in[12];
    const float* W3    = (const float*)d_in[13];
    const float* b3    = (const float*)d_in[14];

    const int B = in_sizes[0] / TT;   // x is [B, T, 1]

    lstm2_pipeline6_kernel<<<dim3(B), dim3(384), 0, stream>>>(
        x, W_ih0, W_hh0, b_ih0, b_hh0, W_ih1, W_hh1, b_ih1, b_hh1,
        W1, b1, W2, b2, W3, b3, (float*)d_out);
}

// Round 3
// 4565.257 us; speedup vs baseline: 1.0697x; 1.0111x over previous
//
#include <hip/hip_runtime.h>

#define TT 512
#define HH 50

__device__ __forceinline__ float sigf(float x) {
    return 1.0f / (1.0f + __expf(-x));
}
__device__ __forceinline__ float tanhfast(float x) {
    // tanh(x) = 1 - 2/(e^{2x}+1); exact limits at +-inf, branch-free
    return 1.0f - 2.0f / (__expf(2.0f * x) + 1.0f);
}

// 2 parallel 50-length dot products: a_g += sum_k w[g][k] * hp[k]
// hp is an LDS pointer, uniform across the wave (broadcast reads, conflict-free).
__device__ __forceinline__ void dot50x2(const float (&w)[2][HH], const float* hp,
                                        float& a0, float& a1) {
#pragma unroll
    for (int q = 0; q < 12; ++q) {
        float4 h4 = *reinterpret_cast<const float4*>(&hp[4 * q]);
        a0 = fmaf(h4.x, w[0][4 * q + 0], a0);
        a0 = fmaf(h4.y, w[0][4 * q + 1], a0);
        a0 = fmaf(h4.z, w[0][4 * q + 2], a0);
        a0 = fmaf(h4.w, w[0][4 * q + 3], a0);
        a1 = fmaf(h4.x, w[1][4 * q + 0], a1);
        a1 = fmaf(h4.y, w[1][4 * q + 1], a1);
        a1 = fmaf(h4.z, w[1][4 * q + 2], a1);
        a1 = fmaf(h4.w, w[1][4 * q + 3], a1);
    }
    float2 h2 = *reinterpret_cast<const float2*>(&hp[48]);
    a0 = fmaf(h2.x, w[0][48], a0); a0 = fmaf(h2.y, w[0][49], a0);
    a1 = fmaf(h2.x, w[1][48], a1); a1 = fmaf(h2.y, w[1][49], a1);
}

// One block = one batch element, 6 waves = 3 pairs:
//   pair p=0: layer0 recurrent (W_hh0), p=1: layer1 input matmul (W_ih1),
//   pair p=2: layer1 recurrent (W_hh1).
// Within a pair, wave s=0 owns gates (i,f), s=1 owns gates (g,o): 100 weights/lane.
// amdgpu_waves_per_eu(4,4): occupancy pinned at 4 waves/EU -> allocator targets
// 128 VGPRs with no incentive to shrink (round-2 failure: it went to 64 and
// rematerialized the weight loads inside the t-loop). The asm pin below makes
// remat illegal outright.
__global__ __launch_bounds__(384)
__attribute__((amdgpu_waves_per_eu(4, 4)))
void lstm2_pipeline6_kernel(const float* __restrict__ x,
                            const float* __restrict__ W_ih0, const float* __restrict__ W_hh0,
                            const float* __restrict__ b_ih0, const float* __restrict__ b_hh0,
                            const float* __restrict__ W_ih1, const float* __restrict__ W_hh1,
                            const float* __restrict__ b_ih1, const float* __restrict__ b_hh1,
                            const float* __restrict__ W1, const float* __restrict__ b1,
                            const float* __restrict__ W2, const float* __restrict__ b2,
                            const float* __restrict__ W3, const float* __restrict__ b3,
                            float* __restrict__ out)
{
    const int b    = blockIdx.x;
    const int tid  = threadIdx.x;
    const int wid  = tid >> 6;     // 0..5
    const int p    = wid >> 1;     // matrix: 0=W_hh0, 1=W_ih1, 2=W_hh1
    const int s    = wid & 1;      // gate half: 0 -> (i,f), 1 -> (g,o)
    const int lane = tid & 63;
    const int js   = (lane < HH) ? lane : 0;   // clamped unit index
    const bool act = (lane < HH);

    __shared__ __align__(16) float h0[52];         // layer0 hidden
    __shared__ __align__(16) float h1[52];         // layer1 hidden
    __shared__ __align__(16) float G0[4][52];      // layer0 gate pre-activations [gate][unit]
    __shared__ __align__(16) float G2[4][52];      // layer1 gate pre-activations
    __shared__ __align__(16) float Bx[2][4][52];   // xg1 double buffer [buf][gate][unit]
    __shared__ float D1[32];
    __shared__ float D2[16];

    if (tid < 52) { h0[tid] = 0.0f; h1[tid] = 0.0f; }

    // --- Stationary weights: lane j of wave (p,s) holds rows {2s*50+j, (2s+1)*50+j} ---
    const float* Wm = (p == 0) ? W_hh0 : (p == 1) ? W_ih1 : W_hh1;
    float w[2][HH];
#pragma unroll
    for (int g = 0; g < 2; ++g) {
        const int row = (2 * s + g) * HH + js;
#pragma unroll
        for (int k = 0; k < HH; ++k)
            w[g][k] = Wm[row * HH + k];
    }

    float bias[2], wx[2];
#pragma unroll
    for (int g = 0; g < 2; ++g) {
        const int r = (2 * s + g) * HH + js;
        bias[g] = (p == 0) ? (b_ih0[r] + b_hh0[r]) : (p == 1) ? b_ih1[r] : b_hh1[r];
        wx[g]   = (p == 0) ? W_ih0[r] : 0.0f;
    }

    // --- Register pin: forbid rematerialization of the stationary values. ---
#pragma unroll
    for (int g = 0; g < 2; ++g) {
#pragma unroll
        for (int k = 0; k < HH; ++k)
            asm volatile("" : "+v"(w[g][k]));
        asm volatile("" : "+v"(bias[g]));
        asm volatile("" : "+v"(wx[g]));
    }

    float c_st = 0.0f;                 // cell state (p0s0: layer0, p2s0: layer1)
    const float* xrow = x + (size_t)b * TT;
    float x_cur = (p == 0) ? xrow[0] : 0.0f;
    float x_nxt = 0.0f;

    __syncthreads();

    for (int tau = 0; tau < TT + 2; ++tau) {
        // ================= M phase: matmuls =================
        if (p == 0) {
            if (tau < TT) {                         // step t = tau, reads h0(t-1)
                if (tau + 1 < TT) x_nxt = xrow[tau + 1];
                float a0 = fmaf(x_cur, wx[0], bias[0]);
                float a1 = fmaf(x_cur, wx[1], bias[1]);
                dot50x2(w, h0, a0, a1);
                if (act) { G0[2 * s][lane] = a0; G0[2 * s + 1][lane] = a1; }
                x_cur = x_nxt;
            }
        } else if (p == 1) {
            if (tau >= 1 && tau <= TT) {            // xg1 for step t = tau-1, reads h0(t)
                float a0 = bias[0], a1 = bias[1];
                dot50x2(w, h0, a0, a1);
                if (act) {
                    Bx[tau & 1][2 * s][lane]     = a0;
                    Bx[tau & 1][2 * s + 1][lane] = a1;
                }
            }
        } else {
            if (tau >= 2) {                         // step t = tau-2, reads h1(t-1), xg1(t)
                const int buf = (tau + 1) & 1;
                float a0 = bias[0] + Bx[buf][2 * s][js];
                float a1 = bias[1] + Bx[buf][2 * s + 1][js];
                dot50x2(w, h1, a0, a1);
                if (act) { G2[2 * s][lane] = a0; G2[2 * s + 1][lane] = a1; }
            }
        }
        __syncthreads();
        // ================= P phase: pointwise =================
        if (s == 0 && act) {
            if (p == 0 && tau < TT) {
                float i = sigf(G0[0][lane]);
                float f = sigf(G0[1][lane]);
                float g = tanhfast(G0[2][lane]);
                float o = sigf(G0[3][lane]);
                c_st = fmaf(f, c_st, i * g);
                h0[lane] = o * tanhfast(c_st);
            } else if (p == 2 && tau >= 2) {
                float i = sigf(G2[0][lane]);
                float f = sigf(G2[1][lane]);
                float g = tanhfast(G2[2][lane]);
                float o = sigf(G2[3][lane]);
                c_st = fmaf(f, c_st, i * g);
                h1[lane] = o * tanhfast(c_st);
            }
        }
        __syncthreads();
    }

    // --- MLP head on final h1 (in LDS); wave 0 computes, barriers hit by all ---
    if (wid == 0 && lane < 32) {
        float z = b1[lane];
#pragma unroll
        for (int k = 0; k < HH; ++k) z = fmaf(W1[lane * HH + k], h1[k], z);
        D1[lane] = fmaxf(z, 0.0f);
    }
    __syncthreads();
    if (wid == 0 && lane < 16) {
        float z = b2[lane];
#pragma unroll
        for (int k = 0; k < 32; ++k) z = fmaf(W2[lane * 32 + k], D1[k], z);
        D2[lane] = fmaxf(z, 0.0f);
    }
    __syncthreads();
    if (wid == 0 && lane == 0) {
        float z = b3[0];
#pragma unroll
        for (int k = 0; k < 16; ++k) z = fmaf(W3[k], D2[k], z);
        out[b] = z;
    }
}

extern "C" void kernel_launch(void* const* d_in, const int* in_sizes, int n_in,
                              void* d_out, int out_size, void* d_ws, size_t ws_size,
                              hipStream_t stream) {
    const float* x     = (const float*)d_in[0];
    const float* W_ih0 = (const float*)d_in[1];
    const float* W_hh0 = (const float*)d_in[2];
    const float* b_ih0 = (const float*)d_in[3];
    const float* b_hh0 = (const float*)d_in[4];
    const float* W_ih1 = (const float*)d_in[5];
    const float* W_hh1 = (const float*)d_in[6];
    const float* b_ih1 = (const float*)d_in[7];
    const float* b_hh1 = (const float*)d_in[8];
    const float* W1    = (const float*)d_in[9];
    const float* b1    = (const float*)d_in[10];
    const float* W2    = (const float*)d_in[11];
    const float* b2    = (const float*)d_in[12];
    const float* W3    = (const float*)d_in[13];
    const float* b3    = (const float*)d_in[14];

    const int B = in_sizes[0] / TT;   // x is [B, T, 1]

    lstm2_pipeline6_kernel<<<dim3(B), dim3(384), 0, stream>>>(
        x, W_ih0, W_hh0, b_ih0, b_hh0, W_ih1, W_hh1, b_ih1, b_hh1,
        W1, b1, W2, b2, W3, b3, (float*)d_out);
}